// Round 3
// baseline (449.355 us; speedup 1.0000x reference)
//
#include <hip/hip_runtime.h>

// Caps layer: B=256 batches, S=512 input caps, D=256 in-dim, NC=16, DC=32, O=512.
// One block per batch, 512 threads (8 waves). All routing state in LDS (60416 B).
// Factorized routing (u_hat never materialized):
//   y[n][D]   = sum_s c[n][s] x[s][D]
//   outputs   = squash_d( y[n] . W[:, n*32+d] )
//   z[n][D]   = sum_d W[D][n*32+d] outputs[n][d]
//   b[n][s]   = sum_D x[s][D] z[n][D]           (MFMA 16x16x32 bf16, fp32 acc)

#define S_ 512
#define D_ 256
#define O_ 512

typedef __attribute__((ext_vector_type(8))) short short8;
typedef __attribute__((ext_vector_type(4))) float floatx4;

__device__ __forceinline__ float b2f(unsigned int u) {
  union { unsigned int i; float f; } v; v.i = u << 16; return v.f;
}
__device__ __forceinline__ unsigned short f2b(float f) {
  union { float ff; unsigned int i; } v; v.ff = f;
  unsigned int u = v.i;
  return (unsigned short)((u + 0x7FFFu + ((u >> 16) & 1u)) >> 16);
}

__global__ __launch_bounds__(512, 4) void caps_kernel(
    const float* __restrict__ x, const float* __restrict__ W,
    float* __restrict__ out)
{
  // LDS: logits f32 16x[520] (33280 B); union (cT bf16 512x16 = 16384 B |
  // ytmp f32 16x260 = 16640 B) -> 16640 B; z bf16 16x[264] (8448 B);
  // outputs f32 [512] (2048 B). Total 60416 B (< 64 KB).
  __shared__ __align__(16) float bl[16 * 520];
  __shared__ __align__(16) unsigned char uni[16640];
  __shared__ __align__(16) unsigned short zb[16 * 264];
  __shared__ __align__(16) float outp[O_];

  unsigned short* cT = (unsigned short*)uni;   // [512][16] bf16 (32 B rows)
  float* ytmp        = (float*)uni;            // [16][260] f32

  const int tid  = threadIdx.x;
  const int wave = tid >> 6;
  const int lane = tid & 63;
  const float* xb = x + (size_t)blockIdx.x * (S_ * D_);

  for (int it = 0; it < 3; ++it) {
    if (it == 0) {
      // ---- iter 0: b=0 -> c = 1/16 uniform -> y[n][:] = (1/16)*rowsum(x), all n equal
      float a0 = 0.f, a1 = 0.f, a2 = 0.f, a3 = 0.f;
      #pragma unroll 4
      for (int r = 0; r < 64; ++r) {
        const int s = (wave << 6) + r;
        const float4 xv = *(const float4*)(xb + s * D_ + (lane << 2));
        a0 += xv.x; a1 += xv.y; a2 += xv.z; a3 += xv.w;
      }
      __syncthreads();
      for (int rr = 0; rr < 8; ++rr) {
        if (wave == rr) {
          float4* p = (float4*)(ytmp + (lane << 2));
          if (rr == 0) { *p = make_float4(a0, a1, a2, a3); }
          else { float4 v = *p; v.x += a0; v.y += a1; v.z += a2; v.w += a3; *p = v; }
        }
        __syncthreads();
      }
      if (tid < 256) {
        const float v = ytmp[tid] * 0.0625f;
        for (int n = 15; n >= 0; --n) ytmp[n * 260 + tid] = v;  // n=0 (self) last
      }
      __syncthreads();
    } else {
      // ---- softmax over n (per s): fp32 logits bl -> cT (bf16, transposed) ----
      {
        const int s = tid;
        float vv[16];
        float m = -1e30f;
        #pragma unroll
        for (int n = 0; n < 16; ++n) { vv[n] = bl[n * 520 + s]; m = fmaxf(m, vv[n]); }
        float sum = 0.f;
        #pragma unroll
        for (int n = 0; n < 16; ++n) { vv[n] = __expf(vv[n] - m); sum += vv[n]; }
        const float inv = 1.f / sum;
        unsigned int w[8];
        #pragma unroll
        for (int j = 0; j < 8; ++j)
          w[j] = (unsigned int)f2b(vv[2*j] * inv) | ((unsigned int)f2b(vv[2*j+1] * inv) << 16);
        *(int4*)(cT + s * 16)     = make_int4(w[0], w[1], w[2], w[3]);
        *(int4*)(cT + s * 16 + 8) = make_int4(w[4], w[5], w[6], w[7]);
      }
      __syncthreads();
      // ---- y-pass: wave owns s-octant, lane owns D-quad; x read once, coalesced
      float acc[16][4];
      #pragma unroll
      for (int n = 0; n < 16; ++n) { acc[n][0] = 0.f; acc[n][1] = 0.f; acc[n][2] = 0.f; acc[n][3] = 0.f; }
      #pragma unroll 2
      for (int r = 0; r < 64; ++r) {
        const int s = (wave << 6) + r;
        const float4 xv = *(const float4*)(xb + s * D_ + (lane << 2));
        const int4 c0 = *(const int4*)(cT + s * 16);      // wave-uniform -> broadcast
        const int4 c1 = *(const int4*)(cT + s * 16 + 8);
        float cf[16];
        cf[0]  = b2f((unsigned int)c0.x & 0xffffu); cf[1]  = b2f((unsigned int)c0.x >> 16);
        cf[2]  = b2f((unsigned int)c0.y & 0xffffu); cf[3]  = b2f((unsigned int)c0.y >> 16);
        cf[4]  = b2f((unsigned int)c0.z & 0xffffu); cf[5]  = b2f((unsigned int)c0.z >> 16);
        cf[6]  = b2f((unsigned int)c0.w & 0xffffu); cf[7]  = b2f((unsigned int)c0.w >> 16);
        cf[8]  = b2f((unsigned int)c1.x & 0xffffu); cf[9]  = b2f((unsigned int)c1.x >> 16);
        cf[10] = b2f((unsigned int)c1.y & 0xffffu); cf[11] = b2f((unsigned int)c1.y >> 16);
        cf[12] = b2f((unsigned int)c1.z & 0xffffu); cf[13] = b2f((unsigned int)c1.z >> 16);
        cf[14] = b2f((unsigned int)c1.w & 0xffffu); cf[15] = b2f((unsigned int)c1.w >> 16);
        #pragma unroll
        for (int n = 0; n < 16; ++n) {
          acc[n][0] += cf[n] * xv.x; acc[n][1] += cf[n] * xv.y;
          acc[n][2] += cf[n] * xv.z; acc[n][3] += cf[n] * xv.w;
        }
      }
      __syncthreads();  // all cT reads done; ytmp may now overwrite the union
      for (int rr = 0; rr < 8; ++rr) {
        if (wave == rr) {
          #pragma unroll
          for (int n = 0; n < 16; ++n) {
            float4* p = (float4*)(ytmp + n * 260 + (lane << 2));
            if (rr == 0) { *p = make_float4(acc[n][0], acc[n][1], acc[n][2], acc[n][3]); }
            else { float4 v = *p; v.x += acc[n][0]; v.y += acc[n][1]; v.z += acc[n][2]; v.w += acc[n][3]; *p = v; }
          }
        }
        __syncthreads();
      }
    }

    // ---- outputs[n][d] = sum_D y[n][D] * W[D][n*32+d], then squash over d ----
    {
      const int o = tid;
      const int n = o >> 5;
      float a = 0.f;
      for (int Db = 0; Db < 32; ++Db) {
        const float4 y0 = *(const float4*)(ytmp + n * 260 + (Db << 3));
        const float4 y1 = *(const float4*)(ytmp + n * 260 + (Db << 3) + 4);
        const float* wp = W + (size_t)(Db << 3) * O_ + o;   // coalesced over tid
        a += y0.x * wp[0 * O_]; a += y0.y * wp[1 * O_];
        a += y0.z * wp[2 * O_]; a += y0.w * wp[3 * O_];
        a += y1.x * wp[4 * O_]; a += y1.y * wp[5 * O_];
        a += y1.z * wp[6 * O_]; a += y1.w * wp[7 * O_];
      }
      float ss = a * a;
      #pragma unroll
      for (int off = 1; off < 32; off <<= 1) ss += __shfl_xor(ss, off, 64);
      const float v = a / sqrtf(ss + 1e-7f);
      outp[o] = v;
      if (it == 2) out[(size_t)blockIdx.x * O_ + o] = v;
    }
    __syncthreads();

    if (it < 2) {
      // ---- z[n][D] = sum_d W[D][n*32+d] * outputs[n][d] ----
      // Wave w owns D in [w*32, w*32+32). Lane 4n+k owns o = n*32+k*8 .. +8.
      {
        const int obase = lane << 3;
        const int n_ln  = lane >> 2;
        float ov[8];
        #pragma unroll
        for (int j = 0; j < 8; ++j) ov[j] = outp[obase + j];
        for (int r = 0; r < 32; ++r) {
          const int Dd = (wave << 5) + r;
          const float4 w0 = *(const float4*)(W + (size_t)Dd * O_ + obase);
          const float4 w1 = *(const float4*)(W + (size_t)Dd * O_ + obase + 4);
          float a = w0.x * ov[0] + w0.y * ov[1] + w0.z * ov[2] + w0.w * ov[3]
                  + w1.x * ov[4] + w1.y * ov[5] + w1.z * ov[6] + w1.w * ov[7];
          a += __shfl_xor(a, 1, 64);
          a += __shfl_xor(a, 2, 64);
          if ((lane & 3) == 0) zb[n_ln * 264 + Dd] = f2b(a);
        }
      }
      __syncthreads();
      // ---- b-update via MFMA: b[16n x 16s] = z[16x256] * x^T[256x16] (bf16, fp32 acc)
      const int l15 = lane & 15, l4 = lane >> 4;
      for (int t = 0; t < 4; ++t) {
        const int s0 = ((wave << 2) + t) << 4;
        floatx4 C = {0.f, 0.f, 0.f, 0.f};
        #pragma unroll
        for (int k = 0; k < 8; ++k) {
          // A-frag: z[m=l15][k*32 + l4*8 + j] from LDS (16B aligned: 528B rows)
          const short8 A = *(const short8*)(zb + l15 * 264 + (k << 5) + (l4 << 3));
          // B-frag: x[s0+l15][k*32 + l4*8 + j] fp32 global -> bf16
          const float* xp = xb + (s0 + l15) * D_ + (k << 5) + (l4 << 3);
          const float4 xv0 = *(const float4*)xp;
          const float4 xv1 = *(const float4*)(xp + 4);
          short8 Bf;
          Bf[0] = (short)f2b(xv0.x); Bf[1] = (short)f2b(xv0.y);
          Bf[2] = (short)f2b(xv0.z); Bf[3] = (short)f2b(xv0.w);
          Bf[4] = (short)f2b(xv1.x); Bf[5] = (short)f2b(xv1.y);
          Bf[6] = (short)f2b(xv1.z); Bf[7] = (short)f2b(xv1.w);
          C = __builtin_amdgcn_mfma_f32_16x16x32_bf16(A, Bf, C, 0, 0, 0);
        }
        // C/D layout: col = lane&15 (s), row = (lane>>4)*4 + reg (n); store fp32
        #pragma unroll
        for (int rg = 0; rg < 4; ++rg)
          bl[((l4 << 2) + rg) * 520 + s0 + l15] = C[rg];
      }
      __syncthreads();
    }
  }
}

extern "C" void kernel_launch(void* const* d_in, const int* in_sizes, int n_in,
                              void* d_out, int out_size, void* d_ws, size_t ws_size,
                              hipStream_t stream) {
  const float* x = (const float*)d_in[0];   // [256, 512, 256] f32
  const float* W = (const float*)d_in[1];   // [256, 512] f32
  float* out = (float*)d_out;               // [256*512] f32
  (void)in_sizes; (void)n_in; (void)out_size; (void)d_ws; (void)ws_size;
  caps_kernel<<<256, 512, 0, stream>>>(x, W, out);
}